// Round 19
// baseline (97.156 us; speedup 1.0000x reference)
//
#include <hip/hip_runtime.h>
#include <hip/hip_fp16.h>
#include <math.h>

#define N_NODES 50000
#define N_EDGES 800000
#define CAP 64     // bucket capacity per node (max degree <= 64, validated r7-r18)
#define NRANGE 782 // ceil(N_NODES/64) ranges of 64 nodes
#define PCAP 1280  // part capacity per range (mean 1023, +8 sigma)
#define EPBA 8192  // edges per partA block (burst coalescing: ~10.5 entries/range)
#define NBA 98     // ceil(N_EDGES/EPBA)
#define NBE 782    // encode blocks: ceil(50000/64)

typedef __attribute__((ext_vector_type(8)))  short s16x8;   // 8 bf16 (4 VGPR)
typedef __attribute__((ext_vector_type(16))) float f32x16;  // MFMA acc
typedef unsigned int u32;
typedef unsigned short u16;

union U16B { uint4 u; s16x8 s; };

// f32 -> bf16 bits, round-to-nearest-even
__device__ __forceinline__ u32 bfr(float f) {
    u32 u = __float_as_uint(f);
    return (u + 0x7FFFu + ((u >> 16) & 1u)) >> 16;
}
__device__ __forceinline__ u32 pkbf(float a, float b) { return bfr(a) | (bfr(b) << 16); }
__device__ __forceinline__ float bf2f(u32 b) { return __uint_as_float(b << 16); }
// dot of a bf16x2 pair against another
__device__ __forceinline__ float dotpair(u32 a, u32 b) {
    return bf2f(a & 0xFFFFu) * bf2f(b & 0xFFFFu) + bf2f(a >> 16) * bf2f(b >> 16);
}

// Build an MFMA input frag (lane-dim = D-col, k = 8*(lane>>5)+e) from 8 f32
// D-regs of a 32x32x16 accumulator (rows (r&3)+8*(r>>2)+4*hh), via bf16 pack
// + half-wave exchange. d8 must be compile-time indexed by caller.
__device__ __forceinline__ uint4 buildfrag(const float* d8, int hh) {
    u32 P = pkbf(d8[0], d8[1]), Q = pkbf(d8[2], d8[3]);
    u32 R = pkbf(d8[4], d8[5]), S = pkbf(d8[6], d8[7]);
    u32 sP = (u32)__shfl_xor((int)P, 32);
    u32 sQ = (u32)__shfl_xor((int)Q, 32);
    u32 sR = (u32)__shfl_xor((int)R, 32);
    u32 sS = (u32)__shfl_xor((int)S, 32);
    uint4 f;
    f.x = hh ? sR : P;  f.y = hh ? sS : Q;
    f.z = hh ? R : sP;  f.w = hh ? S : sQ;
    return f;
}
#define BUILDF(OUT, ACC, Q, HH) do { \
    float _td[8]; \
    _Pragma("unroll") for (int _z = 0; _z < 8; ++_z) _td[_z] = (ACC)[(Q)*8 + _z]; \
    (OUT) = buildfrag(_td, HH); } while (0)
#define BUILDR(OUT, ACC, Q, HH) do { \
    float _td[8]; \
    _Pragma("unroll") for (int _z = 0; _z < 8; ++_z) _td[_z] = fmaxf((ACC)[(Q)*8 + _z], 0.f); \
    (OUT) = buildfrag(_td, HH); } while (0)

// ---------------------------------------------------------------------------
// prep: weights -> bf16, transposed [col][k] rows (256B), granule-XOR swizzled
// Also zeroes gcur (saves the memset dispatch).
// ---------------------------------------------------------------------------
__global__ __launch_bounds__(256) void k_prep(
    const float* __restrict__ enc_w, const float* __restrict__ msg_w,
    const float* __restrict__ sig_w, const float* __restrict__ agg_w,
    const float* __restrict__ dec_w,
    uint4* __restrict__ WtE, uint4* __restrict__ WtM, uint4* __restrict__ WtD,
    uint4* __restrict__ WtA0, uint4* __restrict__ WtA1, uint4* __restrict__ WtS,
    int* __restrict__ gcur)
{
    int gid = blockIdx.x * 256 + threadIdx.x;
    if (gid < NRANGE) gcur[gid] = 0;
    if (gid < 10240) {
        int m = gid >> 11, r = gid & 2047;
        int col = r >> 4, s = r & 15;
        const float* W; uint4* D; int kb = 0;
        if      (m == 0) { W = enc_w; D = WtE; }
        else if (m == 1) { W = msg_w; D = WtM; }
        else if (m == 2) { W = dec_w; D = WtD; }
        else if (m == 3) { W = agg_w; D = WtA0; }
        else             { W = agg_w; D = WtA1; kb = 128; }
        float v[8];
        #pragma unroll
        for (int j = 0; j < 8; ++j) v[j] = W[(size_t)(kb + s * 8 + j) * 128 + col];
        uint4 w;
        w.x = pkbf(v[0], v[1]); w.y = pkbf(v[2], v[3]);
        w.z = pkbf(v[4], v[5]); w.w = pkbf(v[6], v[7]);
        D[col * 16 + (s ^ (col & 7))] = w;
    } else if (gid < 10752) {
        int r = gid - 10240;
        int row = r >> 4, s = r & 15;
        float v[8];
        #pragma unroll
        for (int j = 0; j < 8; ++j)
            v[j] = (row < 16) ? sig_w[(size_t)(s * 8 + j) * 16 + row] : 0.0f;
        uint4 w;
        w.x = pkbf(v[0], v[1]); w.y = pkbf(v[2], v[3]);
        w.z = pkbf(v[4], v[5]); w.w = pkbf(v[6], v[7]);
        WtS[row * 16 + (s ^ (row & 7))] = w;
    }
}

// ---------------------------------------------------------------------------
// fused partA + encode. partA blocks FIRST (blockIdx < NBA) so their
// scattered fabric writes overlap encode's MFMA phase from t=0 instead of
// serializing in the kernel tail.
//   blockIdx <  NBA : LDS radix partition of edges by range r = src>>6
//   blockIdx >= NBA : encode (64-node blocks, 4 waves = node-half x col-half)
// ---------------------------------------------------------------------------
__global__ __launch_bounds__(256) void k_enc_part(
    const float* __restrict__ x,
    const uint4* __restrict__ WtE, const uint4* __restrict__ WtM,
    const uint4* __restrict__ WtS,
    const float* __restrict__ enc_b, const float* __restrict__ sig_b,
    const float* __restrict__ msg_b,
    uint4* __restrict__ h_g, u32* __restrict__ sig_bf, uint4* __restrict__ msg_g,
    const int* __restrict__ src, const int* __restrict__ dst,
    int* __restrict__ gcur, u32* __restrict__ part)
{
    __shared__ uint4 LB[1024];   // x tile / h frags / msg frags / partA hist+base
    __shared__ float LS[1088];   // sig funnel [64][17]

    const int t = threadIdx.x;

    if (blockIdx.x < NBA) {
        // ---------------- partA path ----------------
        int* hist = (int*)LB;
        int* base = hist + NRANGE;
        const int e0 = blockIdx.x * EPBA;
        for (int i = t; i < NRANGE; i += 256) hist[i] = 0;
        __syncthreads();
        #pragma unroll 4
        for (int k = 0; k < EPBA / 256; ++k) {
            int e = e0 + k * 256 + t;
            if (e < N_EDGES) atomicAdd(&hist[src[e] >> 6], 1);
        }
        __syncthreads();
        for (int i = t; i < NRANGE; i += 256) {
            int h = hist[i];
            base[i] = h ? atomicAdd(&gcur[i], h) : 0;
        }
        __syncthreads();
        for (int i = t; i < NRANGE; i += 256) hist[i] = 0;
        __syncthreads();
        #pragma unroll 4
        for (int k = 0; k < EPBA / 256; ++k) {
            int e = e0 + k * 256 + t;
            if (e < N_EDGES) {
                int s = src[e], d = dst[e];
                int r = s >> 6;
                int p = base[r] + atomicAdd(&hist[r], 1);
                part[(size_t)r * PCAP + p] = ((u32)s << 16) | (u32)d;
            }
        }
        return;
    }

    // ---------------- encode path ----------------
    const int node0 = (blockIdx.x - NBA) * 64;
    int nrem = N_NODES - node0; if (nrem > 64) nrem = 64;
    const int lane = t & 63, wid = t >> 6;
    const int l31 = lane & 31, hh = lane >> 5;
    const int ng = wid & 1;        // node half
    const int ch = wid >> 1;       // column half (0: cols 0-63, 1: cols 64-127)
    const int nloc = ng * 32 + l31;
    const int sw7 = l31 & 7;
    const int cb = ch * 64;        // column base

    // stage x (f32->bf16, swizzled): 64 nodes x 16 granules
    #pragma unroll
    for (int it = 0; it < 4; ++it) {
        int idx = it * 256 + t;
        int nd = idx >> 4, s = idx & 15;
        float4 v0 = make_float4(0, 0, 0, 0), v1 = v0;
        if (nd < nrem) {
            const float4* px = (const float4*)(x + (size_t)(node0 + nd) * 128 + s * 8);
            v0 = px[0]; v1 = px[1];
        }
        uint4 w;
        w.x = pkbf(v0.x, v0.y); w.y = pkbf(v0.z, v0.w);
        w.z = pkbf(v1.x, v1.y); w.w = pkbf(v1.z, v1.w);
        LB[nd * 16 + (s ^ (nd & 7))] = w;
    }
    __syncthreads();

    const char* lb = (const char*)LB;
    const char* gwE = (const char*)WtE;
    const char* gwM = (const char*)WtM;
    const char* gwS = (const char*)WtS;

    // GEMM1: h^T (cols cb..cb+63) = encW^T x^T
    f32x16 a0 = {}, a1 = {};
    #pragma unroll
    for (int r = 0; r < 16; ++r) {
        int rr = (r & 3) + 8 * (r >> 2) + 4 * hh;
        a0[r] = enc_b[cb + rr];
        a1[r] = enc_b[cb + 32 + rr];
    }
    #pragma unroll
    for (int ks = 0; ks < 8; ++ks) {
        int so = ((ks * 2 + hh) ^ sw7) << 4;
        s16x8 bf = *(const s16x8*)(lb + nloc * 256 + so);
        s16x8 w0 = *(const s16x8*)(gwE + (cb + l31) * 256 + so);
        s16x8 w1 = *(const s16x8*)(gwE + (cb + 32 + l31) * 256 + so);
        a0 = __builtin_amdgcn_mfma_f32_32x32x16_bf16(w0, bf, a0, 0, 0, 0);
        a1 = __builtin_amdgcn_mfma_f32_32x32x16_bf16(w1, bf, a1, 0, 0, 0);
    }

    // h -> bf16 fragments for this wave's 8 granules [cb/8 .. cb/8+8)
    uint4 hf[4];
    BUILDF(hf[0], a0, 0, hh); BUILDF(hf[1], a0, 1, hh);
    BUILDF(hf[2], a1, 0, hh); BUILDF(hf[3], a1, 1, hh);

    __syncthreads();   // all waves done reading x tile
    // park h frags (swizzled): granules g = ch*8 + {2F+hh, 4+2F+hh}
    #pragma unroll
    for (int f = 0; f < 2; ++f) {
        int g0 = ch * 8 + 2 * f + hh;
        int g1 = ch * 8 + 4 + 2 * f + hh;
        LB[nloc * 16 + (g0 ^ sw7)] = hf[f];
        LB[nloc * 16 + (g1 ^ sw7)] = hf[2 + f];
    }
    __syncthreads();   // full h rows parked

    // GEMM2: msg^T (cols cb..cb+63); B-operand = full h rows from LDS
    f32x16 m0 = {}, m1 = {};
    #pragma unroll
    for (int r = 0; r < 16; ++r) {
        int rr = (r & 3) + 8 * (r >> 2) + 4 * hh;
        m0[r] = msg_b[cb + rr];
        m1[r] = msg_b[cb + 32 + rr];
    }
    #pragma unroll
    for (int ks = 0; ks < 8; ++ks) {
        int so = ((ks * 2 + hh) ^ sw7) << 4;
        s16x8 bf = *(const s16x8*)(lb + nloc * 256 + so);
        s16x8 w0 = *(const s16x8*)(gwM + (cb + l31) * 256 + so);
        s16x8 w1 = *(const s16x8*)(gwM + (cb + 32 + l31) * 256 + so);
        m0 = __builtin_amdgcn_mfma_f32_32x32x16_bf16(w0, bf, m0, 0, 0, 0);
        m1 = __builtin_amdgcn_mfma_f32_32x32x16_bf16(w1, bf, m1, 0, 0, 0);
    }
    uint4 mf[4];
    BUILDR(mf[0], m0, 0, hh); BUILDR(mf[1], m0, 1, hh);
    BUILDR(mf[2], m1, 0, hh); BUILDR(mf[3], m1, 1, hh);

    // GEMM3 (ch==0 waves only): sig^T = sigW^T h^T (B from LDS)
    if (ch == 0) {
        f32x16 sg = {};
        #pragma unroll
        for (int r = 0; r < 8; ++r) {
            int rr = (r & 3) + 8 * (r >> 2) + 4 * hh;   // < 16
            sg[r] = sig_b[rr];
        }
        #pragma unroll
        for (int ks = 0; ks < 8; ++ks) {
            int so = ((ks * 2 + hh) ^ sw7) << 4;
            s16x8 bf = *(const s16x8*)(lb + nloc * 256 + so);
            s16x8 aw = *(const s16x8*)(gwS + l31 * 256 + so);
            sg = __builtin_amdgcn_mfma_f32_32x32x16_bf16(aw, bf, sg, 0, 0, 0);
        }
        float ss = 0.f;
        #pragma unroll
        for (int r = 0; r < 8; ++r) ss += sg[r] * sg[r];
        ss += __shfl_xor(ss, 32);
        float inv = 1.0f / fmaxf(sqrtf(ss), 1e-12f);
        #pragma unroll
        for (int r = 0; r < 8; ++r) {
            int sc = (r & 3) + 8 * (r >> 2) + 4 * hh;
            LS[nloc * 17 + sc] = sg[r] * inv;
        }
    }

    // coalesced h_g write (swizzled rows preserved)
    #pragma unroll
    for (int it = 0; it < 4; ++it) {
        int idx = it * 256 + t;
        if ((idx >> 4) < nrem) h_g[(size_t)node0 * 16 + idx] = LB[idx];
    }
    __syncthreads();   // all LB h reads (GEMM2/3 + dump) done

    // park msg frags (LINEAR granule layout)
    #pragma unroll
    for (int f = 0; f < 2; ++f) {
        LB[nloc * 16 + cb / 8 + 2 * f + hh]     = mf[f];
        LB[nloc * 16 + cb / 8 + 4 + 2 * f + hh] = mf[2 + f];
    }
    __syncthreads();

    // coalesced msg_g write + sig dump
    #pragma unroll
    for (int it = 0; it < 4; ++it) {
        int idx = it * 256 + t;
        if ((idx >> 4) < nrem) msg_g[(size_t)node0 * 16 + idx] = LB[idx];
    }
    #pragma unroll
    for (int it = 0; it < 2; ++it) {
        int idx = it * 256 + t;           // 512 = 64 nodes x 8 u32
        int nd = idx >> 3, c2 = idx & 7;
        if (nd < nrem)
            sig_bf[(size_t)(node0 + nd) * 8 + c2] =
                pkbf(LS[nd * 17 + 2 * c2], LS[nd * 17 + 2 * c2 + 1]);
    }
}

// ---------------------------------------------------------------------------
// decode (MFMA): out = relu([h|comm]@agg_w+b) @ dec_w + b
// Block = 64 nodes, 4 waves: wave = (node half) x (64 col half).
// ---------------------------------------------------------------------------
__global__ __launch_bounds__(256) void k_decode_m(
    const uint4* __restrict__ h_g, const uint4* __restrict__ comm,
    const uint4* __restrict__ WtA0, const uint4* __restrict__ WtA1,
    const uint4* __restrict__ WtD,
    const float* __restrict__ agg_b, const float* __restrict__ dec_b,
    float* __restrict__ out)
{
    __shared__ uint4 LB[2048];   // Bcat [64][32 granules]; later Lcomb [64][16]
    __shared__ uint4 LW[2048];

    const int t = threadIdx.x;
    const int node0 = blockIdx.x * 64;
    int nrem = N_NODES - node0; if (nrem > 64) nrem = 64;
    const int lane = t & 63, wid = t >> 6;
    const int l31 = lane & 31, hh = lane >> 5;
    const int ng = wid & 1, cp = wid >> 1;
    const int nloc = ng * 32 + l31;
    const int sw7 = l31 & 7;

    // stage Bcat = [h | comm] bf16 (both pre-swizzled: linear copy)
    #pragma unroll
    for (int it = 0; it < 8; ++it) {
        int idx = it * 256 + t;
        int nd = idx >> 5, g = idx & 31;
        uint4 v = make_uint4(0, 0, 0, 0);
        if (nd < nrem)
            v = (g < 16) ? h_g[(size_t)(node0 + nd) * 16 + g]
                         : comm[(size_t)(node0 + nd) * 16 + (g - 16)];
        LB[nd * 32 + g] = v;
        LW[idx] = WtA0[idx];
    }
    __syncthreads();

    const char* lb = (const char*)LB;
    const char* lw = (const char*)LW;

    // GEMM-A: combined^T = aggW^T [h|comm]^T  (K = 256, staged in halves)
    f32x16 c0 = {}, c1 = {};
    #pragma unroll
    for (int r = 0; r < 16; ++r) {
        int rr = (r & 3) + 8 * (r >> 2) + 4 * hh;
        c0[r] = agg_b[cp * 64 + rr];
        c1[r] = agg_b[cp * 64 + 32 + rr];
    }
    #pragma unroll
    for (int ks = 0; ks < 8; ++ks) {
        int so = ((ks * 2 + hh) ^ sw7) << 4;
        s16x8 bf = *(const s16x8*)(lb + nloc * 512 + so);
        s16x8 w0 = *(const s16x8*)(lw + (cp * 64 + l31) * 256 + so);
        s16x8 w1 = *(const s16x8*)(lw + (cp * 64 + 32 + l31) * 256 + so);
        c0 = __builtin_amdgcn_mfma_f32_32x32x16_bf16(w0, bf, c0, 0, 0, 0);
        c1 = __builtin_amdgcn_mfma_f32_32x32x16_bf16(w1, bf, c1, 0, 0, 0);
    }
    __syncthreads();
    #pragma unroll
    for (int it = 0; it < 8; ++it) LW[it * 256 + t] = WtA1[it * 256 + t];
    __syncthreads();
    #pragma unroll
    for (int ks = 8; ks < 16; ++ks) {
        int so = ((ks * 2 + hh) ^ sw7) << 4;            // bit4 kept: comm half
        int so2 = (((ks - 8) * 2 + hh) ^ sw7) << 4;
        s16x8 bf = *(const s16x8*)(lb + nloc * 512 + so);
        s16x8 w0 = *(const s16x8*)(lw + (cp * 64 + l31) * 256 + so2);
        s16x8 w1 = *(const s16x8*)(lw + (cp * 64 + 32 + l31) * 256 + so2);
        c0 = __builtin_amdgcn_mfma_f32_32x32x16_bf16(w0, bf, c0, 0, 0, 0);
        c1 = __builtin_amdgcn_mfma_f32_32x32x16_bf16(w1, bf, c1, 0, 0, 0);
    }
    __syncthreads();   // all Bcat / WtA1 reads done

    // relu + build combined fragments; exchange across waves via LB (Lcomb)
    {
        uint4 cf[4];
        BUILDR(cf[0], c0, 0, hh); BUILDR(cf[1], c0, 1, hh);
        BUILDR(cf[2], c1, 0, hh); BUILDR(cf[3], c1, 1, hh);
        #pragma unroll
        for (int f = 0; f < 4; ++f) {
            int g = (cp * 4 + f) * 2 + hh;
            LB[nloc * 16 + (g ^ sw7)] = cf[f];
        }
    }
    #pragma unroll
    for (int it = 0; it < 8; ++it) LW[it * 256 + t] = WtD[it * 256 + t];
    __syncthreads();

    // GEMM-B: out = combined @ dec_w  (A = in-LDS combined frags, lane = outcol)
    f32x16 o0 = {}, o1 = {};
    {
        float b0 = dec_b[cp * 64 + l31], b1 = dec_b[cp * 64 + 32 + l31];
        #pragma unroll
        for (int r = 0; r < 16; ++r) { o0[r] = b0; o1[r] = b1; }
    }
    #pragma unroll
    for (int ks = 0; ks < 8; ++ks) {
        int so = ((ks * 2 + hh) ^ sw7) << 4;
        s16x8 af = *(const s16x8*)(lb + nloc * 256 + so);
        s16x8 w0 = *(const s16x8*)(lw + (cp * 64 + l31) * 256 + so);
        s16x8 w1 = *(const s16x8*)(lw + (cp * 64 + 32 + l31) * 256 + so);
        o0 = __builtin_amdgcn_mfma_f32_32x32x16_bf16(af, w0, o0, 0, 0, 0);
        o1 = __builtin_amdgcn_mfma_f32_32x32x16_bf16(af, w1, o1, 0, 0, 0);
    }
    #pragma unroll
    for (int r = 0; r < 16; ++r) {
        int nd = ng * 32 + (r & 3) + 8 * (r >> 2) + 4 * hh;
        if (nd < nrem) {
            float* row = out + (size_t)(node0 + nd) * 128 + cp * 64;
            row[l31]      = o0[r];
            row[32 + l31] = o1[r];
        }
    }
}

// ---------------------------------------------------------------------------
// fused partB + aggr: one block per 64-node range. LDS ~17 KB.
//  phase 1: bin entries into LDS; den (f32) via LDS atomics
//  phase 2: PV — 2 nodes/wave (half-wave, lane = 4 dims), 4-way unrolled
//           batched independent gathers.
// ---------------------------------------------------------------------------
__global__ __launch_bounds__(256) void k_pb_aggr(
    const int* __restrict__ gcur, const u32* __restrict__ part,
    const u32* __restrict__ sig_bf,
    const char* __restrict__ msg_g, char* __restrict__ comm)
{
    __shared__ int   cnt[64];
    __shared__ float lden[64];
    __shared__ u32   lde[64 * CAP];   // 16 KB packed (d | fp16(e)<<16)

    const int t = threadIdx.x;
    const int r = blockIdx.x;
    const int node0 = r * 64;

    if (t < 64) { cnt[t] = 0; lden[t] = 0.f; }
    __syncthreads();

    const int total = gcur[r];
    for (int i = t; i < total; i += 256) {
        u32 en = part[(size_t)r * PCAP + i];
        int s = (int)(en >> 16), d = (int)(en & 0xFFFFu);
        const uint4* ps = (const uint4*)(sig_bf + (size_t)s * 8);
        const uint4* pd = (const uint4*)(sig_bf + (size_t)d * 8);
        uint4 sa = ps[0], sb = ps[1];
        uint4 da = pd[0], db = pd[1];
        float dot = dotpair(sa.x, da.x) + dotpair(sa.y, da.y)
                  + dotpair(sa.z, da.z) + dotpair(sa.w, da.w)
                  + dotpair(sb.x, db.x) + dotpair(sb.y, db.y)
                  + dotpair(sb.z, db.z) + dotpair(sb.w, db.w);
        float e = __expf(dot);   // |dot|<=1 (unit sigs): segment_max elision exact
        int sl = s & 63;
        int p = atomicAdd(&cnt[sl], 1);
        lde[sl * CAP + p] = (u32)d | ((u32)__half_as_ushort(__float2half(e)) << 16);
        atomicAdd(&lden[sl], e);
    }
    __syncthreads();

    // PV: wave wid covers nodes [wid*16, wid*16+16), 2 at a time (half-waves)
    const int lane = t & 63, wid = t >> 6;
    const int l31 = lane & 31, hh = lane >> 5;
    #pragma unroll
    for (int g = 0; g < 8; ++g) {
        const int nloc = wid * 16 + 2 * g + hh;
        const int node = node0 + nloc;
        const int cn = cnt[nloc];
        const u32* ld = &lde[nloc * CAP];
        float a0 = 0.f, a1 = 0.f, a2 = 0.f, a3 = 0.f;
        int k = 0;
        for (; k + 4 <= cn; k += 4) {
            u32 b0 = ld[k], b1 = ld[k + 1], b2 = ld[k + 2], b3 = ld[k + 3];
            uint2 m0 = *(const uint2*)(msg_g + (size_t)(b0 & 0xFFFFu) * 256 + 8 * l31);
            uint2 m1 = *(const uint2*)(msg_g + (size_t)(b1 & 0xFFFFu) * 256 + 8 * l31);
            uint2 m2 = *(const uint2*)(msg_g + (size_t)(b2 & 0xFFFFu) * 256 + 8 * l31);
            uint2 m3 = *(const uint2*)(msg_g + (size_t)(b3 & 0xFFFFu) * 256 + 8 * l31);
            float e0 = __half2float(__ushort_as_half((u16)(b0 >> 16)));
            float e1 = __half2float(__ushort_as_half((u16)(b1 >> 16)));
            float e2 = __half2float(__ushort_as_half((u16)(b2 >> 16)));
            float e3 = __half2float(__ushort_as_half((u16)(b3 >> 16)));
            a0 += e0 * bf2f(m0.x & 0xFFFFu); a1 += e0 * bf2f(m0.x >> 16);
            a2 += e0 * bf2f(m0.y & 0xFFFFu); a3 += e0 * bf2f(m0.y >> 16);
            a0 += e1 * bf2f(m1.x & 0xFFFFu); a1 += e1 * bf2f(m1.x >> 16);
            a2 += e1 * bf2f(m1.y & 0xFFFFu); a3 += e1 * bf2f(m1.y >> 16);
            a0 += e2 * bf2f(m2.x & 0xFFFFu); a1 += e2 * bf2f(m2.x >> 16);
            a2 += e2 * bf2f(m2.y & 0xFFFFu); a3 += e2 * bf2f(m2.y >> 16);
            a0 += e3 * bf2f(m3.x & 0xFFFFu); a1 += e3 * bf2f(m3.x >> 16);
            a2 += e3 * bf2f(m3.y & 0xFFFFu); a3 += e3 * bf2f(m3.y >> 16);
        }
        for (; k < cn; ++k) {
            u32 b = ld[k];
            float e = __half2float(__ushort_as_half((u16)(b >> 16)));
            uint2 m = *(const uint2*)(msg_g + (size_t)(b & 0xFFFFu) * 256 + 8 * l31);
            a0 += e * bf2f(m.x & 0xFFFFu);
            a1 += e * bf2f(m.x >> 16);
            a2 += e * bf2f(m.y & 0xFFFFu);
            a3 += e * bf2f(m.y >> 16);
        }
        float den = lden[nloc];
        float inv = (den > 0.f) ? (1.0f / den) : 0.f;
        if (node < N_NODES) {
            uint2 w;
            w.x = pkbf(a0 * inv, a1 * inv);
            w.y = pkbf(a2 * inv, a3 * inv);
            *(uint2*)(comm + (size_t)node * 256 + ((8 * l31) ^ ((node & 7) << 4))) = w;
        }
    }
}

// ---------------------------------------------------------------------------
extern "C" void kernel_launch(void* const* d_in, const int* in_sizes, int n_in,
                              void* d_out, int out_size, void* d_ws, size_t ws_size,
                              hipStream_t stream)
{
    const float* x     = (const float*)d_in[0];
    const int*   ei    = (const int*)  d_in[1];
    const float* enc_w = (const float*)d_in[2];
    const float* enc_b = (const float*)d_in[3];
    const float* sig_w = (const float*)d_in[4];
    const float* sig_b = (const float*)d_in[5];
    const float* msg_w = (const float*)d_in[6];
    const float* msg_b = (const float*)d_in[7];
    const float* agg_w = (const float*)d_in[8];
    const float* agg_b = (const float*)d_in[9];
    const float* dec_w = (const float*)d_in[10];
    const float* dec_b = (const float*)d_in[11];
    float* out = (float*)d_out;

    const int* src = ei;            // edge_index[0]
    const int* dst = ei + N_EDGES;  // edge_index[1]

    // workspace layout (bytes), ~45 MB
    char* p = (char*)d_ws;
    uint4* h_g   = (uint4*)p;  p += (size_t)N_NODES * 256;  // bf16 rows, swizzled
    uint4* msg_g = (uint4*)p;  p += (size_t)N_NODES * 256;  // bf16 rows, LINEAR
    uint4* comm  = (uint4*)p;  p += (size_t)N_NODES * 256;  // bf16 rows, swizzled
    u32*   sig_bf = (u32*)p;   p += (size_t)N_NODES * 32;   // bf16 sig rows
    u32*   part   = (u32*)p;   p += (size_t)NRANGE * PCAP * 4;
    int*   gcur   = (int*)p;   p += 4096;
    uint4* WtE  = (uint4*)p; p += 32768;
    uint4* WtM  = (uint4*)p; p += 32768;
    uint4* WtD  = (uint4*)p; p += 32768;
    uint4* WtA0 = (uint4*)p; p += 32768;
    uint4* WtA1 = (uint4*)p; p += 32768;
    uint4* WtS  = (uint4*)p; p += 8192;

    k_prep<<<42, 256, 0, stream>>>(enc_w, msg_w, sig_w, agg_w, dec_w,
                                   WtE, WtM, WtD, WtA0, WtA1, WtS, gcur);
    k_enc_part<<<NBA + NBE, 256, 0, stream>>>(
        x, WtE, WtM, WtS, enc_b, sig_b, msg_b, h_g, sig_bf, msg_g,
        src, dst, gcur, part);
    k_pb_aggr<<<NRANGE, 256, 0, stream>>>(
        gcur, part, sig_bf, (const char*)msg_g, (char*)comm);
    k_decode_m<<<(N_NODES + 63) / 64, 256, 0, stream>>>(
        h_g, comm, WtA0, WtA1, WtD, agg_b, dec_b, out);
}

// Round 20
// 96.913 us; speedup vs baseline: 1.0025x; 1.0025x over previous
//
#include <hip/hip_runtime.h>
#include <hip/hip_fp16.h>
#include <math.h>

#define N_NODES 50000
#define N_EDGES 800000
#define CAP 64     // bucket capacity per node (max degree <= 64, validated r7-r19)
#define NRANGE 782 // ceil(N_NODES/64) ranges of 64 nodes
#define PCAP 1280  // part capacity per range (mean 1023, +8 sigma)
#define EPBA 8192  // edges per partA block
#define NBA 98     // ceil(N_EDGES/EPBA)
#define NBE 782    // encode blocks: ceil(50000/64)

typedef __attribute__((ext_vector_type(8)))  short s16x8;   // 8 bf16 (4 VGPR)
typedef __attribute__((ext_vector_type(16))) float f32x16;  // MFMA acc
typedef unsigned int u32;
typedef unsigned short u16;

union U16B { uint4 u; s16x8 s; };

// f32 -> bf16 bits, round-to-nearest-even
__device__ __forceinline__ u32 bfr(float f) {
    u32 u = __float_as_uint(f);
    return (u + 0x7FFFu + ((u >> 16) & 1u)) >> 16;
}
__device__ __forceinline__ u32 pkbf(float a, float b) { return bfr(a) | (bfr(b) << 16); }
__device__ __forceinline__ float bf2f(u32 b) { return __uint_as_float(b << 16); }
// dot of a bf16x2 pair against another
__device__ __forceinline__ float dotpair(u32 a, u32 b) {
    return bf2f(a & 0xFFFFu) * bf2f(b & 0xFFFFu) + bf2f(a >> 16) * bf2f(b >> 16);
}

// Build an MFMA input frag (lane-dim = D-col, k = 8*(lane>>5)+e) from 8 f32
// D-regs of a 32x32x16 accumulator (rows (r&3)+8*(r>>2)+4*hh), via bf16 pack
// + half-wave exchange. d8 must be compile-time indexed by caller.
__device__ __forceinline__ uint4 buildfrag(const float* d8, int hh) {
    u32 P = pkbf(d8[0], d8[1]), Q = pkbf(d8[2], d8[3]);
    u32 R = pkbf(d8[4], d8[5]), S = pkbf(d8[6], d8[7]);
    u32 sP = (u32)__shfl_xor((int)P, 32);
    u32 sQ = (u32)__shfl_xor((int)Q, 32);
    u32 sR = (u32)__shfl_xor((int)R, 32);
    u32 sS = (u32)__shfl_xor((int)S, 32);
    uint4 f;
    f.x = hh ? sR : P;  f.y = hh ? sS : Q;
    f.z = hh ? R : sP;  f.w = hh ? S : sQ;
    return f;
}
#define BUILDF(OUT, ACC, Q, HH) do { \
    float _td[8]; \
    _Pragma("unroll") for (int _z = 0; _z < 8; ++_z) _td[_z] = (ACC)[(Q)*8 + _z]; \
    (OUT) = buildfrag(_td, HH); } while (0)
#define BUILDR(OUT, ACC, Q, HH) do { \
    float _td[8]; \
    _Pragma("unroll") for (int _z = 0; _z < 8; ++_z) _td[_z] = fmaxf((ACC)[(Q)*8 + _z], 0.f); \
    (OUT) = buildfrag(_td, HH); } while (0)

// ---------------------------------------------------------------------------
// prep: decode weights (D/A0/A1) in row-swizzled layout (unchanged);
// encode weights (E/M/S) in FRAGMENT-LINEAR layout: for each MFMA instr slot
// (ch, acc, ks) a contiguous 1KB block of the 64 lanes' 16B fragments
//   entry(l) = W[granule 2ks+(l>>5)][col = ch*64 + acc*32 + (l&31)]
// so each wave weight-load is one coalesced 1KB read. Also zeroes gcur.
// ---------------------------------------------------------------------------
__global__ __launch_bounds__(256) void k_prep(
    const float* __restrict__ enc_w, const float* __restrict__ msg_w,
    const float* __restrict__ sig_w, const float* __restrict__ agg_w,
    const float* __restrict__ dec_w,
    uint4* __restrict__ WtE, uint4* __restrict__ WtM, uint4* __restrict__ WtD,
    uint4* __restrict__ WtA0, uint4* __restrict__ WtA1, uint4* __restrict__ WtS,
    int* __restrict__ gcur)
{
    int gid = blockIdx.x * 256 + threadIdx.x;
    if (gid < NRANGE) gcur[gid] = 0;
    if (gid < 4096) {
        // ---- frag-linear E (0..2047) and M (2048..4095) ----
        const float* W = (gid < 2048) ? enc_w : msg_w;
        uint4* D = (gid < 2048) ? WtE : WtM;
        int e = gid & 2047;
        int l = e & 63, blk = e >> 6;          // blk: [ch:1][acc:1][ks:3] -> 32
        int ks = blk & 7, a = (blk >> 3) & 1, ch = blk >> 4;
        int col = ch * 64 + a * 32 + (l & 31);
        int g = 2 * ks + (l >> 5);
        float v[8];
        #pragma unroll
        for (int j = 0; j < 8; ++j) v[j] = W[(size_t)(g * 8 + j) * 128 + col];
        uint4 w;
        w.x = pkbf(v[0], v[1]); w.y = pkbf(v[2], v[3]);
        w.z = pkbf(v[4], v[5]); w.w = pkbf(v[6], v[7]);
        D[e] = w;
    } else if (gid < 10240) {
        // ---- row-swizzled D / A0 / A1 (decode layout, unchanged) ----
        int m = (gid - 4096) >> 11;            // 0: D, 1: A0, 2: A1
        int r = gid & 2047;
        int col = r >> 4, s = r & 15;
        const float* W; uint4* D; int kb = 0;
        if      (m == 0) { W = dec_w; D = WtD; }
        else if (m == 1) { W = agg_w; D = WtA0; }
        else             { W = agg_w; D = WtA1; kb = 128; }
        float v[8];
        #pragma unroll
        for (int j = 0; j < 8; ++j) v[j] = W[(size_t)(kb + s * 8 + j) * 128 + col];
        uint4 w;
        w.x = pkbf(v[0], v[1]); w.y = pkbf(v[2], v[3]);
        w.z = pkbf(v[4], v[5]); w.w = pkbf(v[6], v[7]);
        D[col * 16 + (s ^ (col & 7))] = w;
    } else if (gid < 10752) {
        // ---- frag-linear S (512 entries: [ks:3][lane:6]) ----
        int e = gid - 10240;
        int l = e & 63, ks = e >> 6;
        int col16 = l & 31;
        int g = 2 * ks + (l >> 5);
        float v[8];
        #pragma unroll
        for (int j = 0; j < 8; ++j)
            v[j] = (col16 < 16) ? sig_w[(size_t)(g * 8 + j) * 16 + col16] : 0.0f;
        uint4 w;
        w.x = pkbf(v[0], v[1]); w.y = pkbf(v[2], v[3]);
        w.z = pkbf(v[4], v[5]); w.w = pkbf(v[6], v[7]);
        WtS[e] = w;
    }
}

// ---------------------------------------------------------------------------
// fused partA + encode. partA blocks FIRST (overlap encode's MFMA phase).
// Encode: 64-node blocks, 4 waves = (node half) x (col half); weight loads
// are frag-linear 1KB coalesced reads.
// ---------------------------------------------------------------------------
__global__ __launch_bounds__(256) void k_enc_part(
    const float* __restrict__ x,
    const uint4* __restrict__ WtE, const uint4* __restrict__ WtM,
    const uint4* __restrict__ WtS,
    const float* __restrict__ enc_b, const float* __restrict__ sig_b,
    const float* __restrict__ msg_b,
    uint4* __restrict__ h_g, u32* __restrict__ sig_bf, uint4* __restrict__ msg_g,
    const int* __restrict__ src, const int* __restrict__ dst,
    int* __restrict__ gcur, u32* __restrict__ part)
{
    __shared__ uint4 LB[1024];   // x tile / h frags / msg frags / partA hist+base
    __shared__ float LS[1088];   // sig funnel [64][17]

    const int t = threadIdx.x;

    if (blockIdx.x < NBA) {
        // ---------------- partA path ----------------
        int* hist = (int*)LB;
        int* base = hist + NRANGE;
        const int e0 = blockIdx.x * EPBA;
        for (int i = t; i < NRANGE; i += 256) hist[i] = 0;
        __syncthreads();
        #pragma unroll 4
        for (int k = 0; k < EPBA / 256; ++k) {
            int e = e0 + k * 256 + t;
            if (e < N_EDGES) atomicAdd(&hist[src[e] >> 6], 1);
        }
        __syncthreads();
        for (int i = t; i < NRANGE; i += 256) {
            int h = hist[i];
            base[i] = h ? atomicAdd(&gcur[i], h) : 0;
        }
        __syncthreads();
        for (int i = t; i < NRANGE; i += 256) hist[i] = 0;
        __syncthreads();
        #pragma unroll 4
        for (int k = 0; k < EPBA / 256; ++k) {
            int e = e0 + k * 256 + t;
            if (e < N_EDGES) {
                int s = src[e], d = dst[e];
                int r = s >> 6;
                int p = base[r] + atomicAdd(&hist[r], 1);
                part[(size_t)r * PCAP + p] = ((u32)s << 16) | (u32)d;
            }
        }
        return;
    }

    // ---------------- encode path ----------------
    const int node0 = (blockIdx.x - NBA) * 64;
    int nrem = N_NODES - node0; if (nrem > 64) nrem = 64;
    const int lane = t & 63, wid = t >> 6;
    const int l31 = lane & 31, hh = lane >> 5;
    const int ng = wid & 1;        // node half
    const int ch = wid >> 1;       // column half (0: cols 0-63, 1: cols 64-127)
    const int nloc = ng * 32 + l31;
    const int sw7 = l31 & 7;
    const int cb = ch * 64;        // column base

    // stage x (f32->bf16, swizzled): 64 nodes x 16 granules
    #pragma unroll
    for (int it = 0; it < 4; ++it) {
        int idx = it * 256 + t;
        int nd = idx >> 4, s = idx & 15;
        float4 v0 = make_float4(0, 0, 0, 0), v1 = v0;
        if (nd < nrem) {
            const float4* px = (const float4*)(x + (size_t)(node0 + nd) * 128 + s * 8);
            v0 = px[0]; v1 = px[1];
        }
        uint4 w;
        w.x = pkbf(v0.x, v0.y); w.y = pkbf(v0.z, v0.w);
        w.z = pkbf(v1.x, v1.y); w.w = pkbf(v1.z, v1.w);
        LB[nd * 16 + (s ^ (nd & 7))] = w;
    }
    __syncthreads();

    const char* lb = (const char*)LB;
    const uint4* gwE = WtE + ch * 1024;   // this col-half's 16 frag blocks
    const uint4* gwM = WtM + ch * 1024;

    // GEMM1: h^T (cols cb..cb+63) = encW^T x^T  (frag-linear weight loads)
    f32x16 a0 = {}, a1 = {};
    #pragma unroll
    for (int r = 0; r < 16; ++r) {
        int rr = (r & 3) + 8 * (r >> 2) + 4 * hh;
        a0[r] = enc_b[cb + rr];
        a1[r] = enc_b[cb + 32 + rr];
    }
    #pragma unroll
    for (int ks = 0; ks < 8; ++ks) {
        int so = ((ks * 2 + hh) ^ sw7) << 4;
        s16x8 bf = *(const s16x8*)(lb + nloc * 256 + so);
        U16B u0, u1;
        u0.u = gwE[ks * 64 + lane];
        u1.u = gwE[(8 + ks) * 64 + lane];
        a0 = __builtin_amdgcn_mfma_f32_32x32x16_bf16(u0.s, bf, a0, 0, 0, 0);
        a1 = __builtin_amdgcn_mfma_f32_32x32x16_bf16(u1.s, bf, a1, 0, 0, 0);
    }

    // h -> bf16 fragments for this wave's 8 granules [cb/8 .. cb/8+8)
    uint4 hf[4];
    BUILDF(hf[0], a0, 0, hh); BUILDF(hf[1], a0, 1, hh);
    BUILDF(hf[2], a1, 0, hh); BUILDF(hf[3], a1, 1, hh);

    __syncthreads();   // all waves done reading x tile
    // park h frags (swizzled): granules g = ch*8 + {2F+hh, 4+2F+hh}
    #pragma unroll
    for (int f = 0; f < 2; ++f) {
        int g0 = ch * 8 + 2 * f + hh;
        int g1 = ch * 8 + 4 + 2 * f + hh;
        LB[nloc * 16 + (g0 ^ sw7)] = hf[f];
        LB[nloc * 16 + (g1 ^ sw7)] = hf[2 + f];
    }
    __syncthreads();   // full h rows parked

    // GEMM2: msg^T (cols cb..cb+63); B-operand = full h rows from LDS
    f32x16 m0 = {}, m1 = {};
    #pragma unroll
    for (int r = 0; r < 16; ++r) {
        int rr = (r & 3) + 8 * (r >> 2) + 4 * hh;
        m0[r] = msg_b[cb + rr];
        m1[r] = msg_b[cb + 32 + rr];
    }
    #pragma unroll
    for (int ks = 0; ks < 8; ++ks) {
        int so = ((ks * 2 + hh) ^ sw7) << 4;
        s16x8 bf = *(const s16x8*)(lb + nloc * 256 + so);
        U16B u0, u1;
        u0.u = gwM[ks * 64 + lane];
        u1.u = gwM[(8 + ks) * 64 + lane];
        m0 = __builtin_amdgcn_mfma_f32_32x32x16_bf16(u0.s, bf, m0, 0, 0, 0);
        m1 = __builtin_amdgcn_mfma_f32_32x32x16_bf16(u1.s, bf, m1, 0, 0, 0);
    }
    uint4 mf[4];
    BUILDR(mf[0], m0, 0, hh); BUILDR(mf[1], m0, 1, hh);
    BUILDR(mf[2], m1, 0, hh); BUILDR(mf[3], m1, 1, hh);

    // GEMM3 (ch==0 waves only): sig^T = sigW^T h^T (B from LDS)
    if (ch == 0) {
        f32x16 sg = {};
        #pragma unroll
        for (int r = 0; r < 8; ++r) {
            int rr = (r & 3) + 8 * (r >> 2) + 4 * hh;   // < 16
            sg[r] = sig_b[rr];
        }
        #pragma unroll
        for (int ks = 0; ks < 8; ++ks) {
            int so = ((ks * 2 + hh) ^ sw7) << 4;
            s16x8 bf = *(const s16x8*)(lb + nloc * 256 + so);
            U16B uw; uw.u = WtS[ks * 64 + lane];
            sg = __builtin_amdgcn_mfma_f32_32x32x16_bf16(uw.s, bf, sg, 0, 0, 0);
        }
        float ss = 0.f;
        #pragma unroll
        for (int r = 0; r < 8; ++r) ss += sg[r] * sg[r];
        ss += __shfl_xor(ss, 32);
        float inv = 1.0f / fmaxf(sqrtf(ss), 1e-12f);
        #pragma unroll
        for (int r = 0; r < 8; ++r) {
            int sc = (r & 3) + 8 * (r >> 2) + 4 * hh;
            LS[nloc * 17 + sc] = sg[r] * inv;
        }
    }

    // coalesced h_g write (swizzled rows preserved)
    #pragma unroll
    for (int it = 0; it < 4; ++it) {
        int idx = it * 256 + t;
        if ((idx >> 4) < nrem) h_g[(size_t)node0 * 16 + idx] = LB[idx];
    }
    __syncthreads();   // all LB h reads (GEMM2/3 + dump) done

    // park msg frags (LINEAR granule layout)
    #pragma unroll
    for (int f = 0; f < 2; ++f) {
        LB[nloc * 16 + cb / 8 + 2 * f + hh]     = mf[f];
        LB[nloc * 16 + cb / 8 + 4 + 2 * f + hh] = mf[2 + f];
    }
    __syncthreads();

    // coalesced msg_g write + sig dump
    #pragma unroll
    for (int it = 0; it < 4; ++it) {
        int idx = it * 256 + t;
        if ((idx >> 4) < nrem) msg_g[(size_t)node0 * 16 + idx] = LB[idx];
    }
    #pragma unroll
    for (int it = 0; it < 2; ++it) {
        int idx = it * 256 + t;           // 512 = 64 nodes x 8 u32
        int nd = idx >> 3, c2 = idx & 7;
        if (nd < nrem)
            sig_bf[(size_t)(node0 + nd) * 8 + c2] =
                pkbf(LS[nd * 17 + 2 * c2], LS[nd * 17 + 2 * c2 + 1]);
    }
}

// ---------------------------------------------------------------------------
// decode (MFMA): out = relu([h|comm]@agg_w+b) @ dec_w + b
// Block = 64 nodes, 4 waves: wave = (node half) x (64 col half).
// ---------------------------------------------------------------------------
__global__ __launch_bounds__(256) void k_decode_m(
    const uint4* __restrict__ h_g, const uint4* __restrict__ comm,
    const uint4* __restrict__ WtA0, const uint4* __restrict__ WtA1,
    const uint4* __restrict__ WtD,
    const float* __restrict__ agg_b, const float* __restrict__ dec_b,
    float* __restrict__ out)
{
    __shared__ uint4 LB[2048];   // Bcat [64][32 granules]; later Lcomb [64][16]
    __shared__ uint4 LW[2048];

    const int t = threadIdx.x;
    const int node0 = blockIdx.x * 64;
    int nrem = N_NODES - node0; if (nrem > 64) nrem = 64;
    const int lane = t & 63, wid = t >> 6;
    const int l31 = lane & 31, hh = lane >> 5;
    const int ng = wid & 1, cp = wid >> 1;
    const int nloc = ng * 32 + l31;
    const int sw7 = l31 & 7;

    // stage Bcat = [h | comm] bf16 (both pre-swizzled: linear copy)
    #pragma unroll
    for (int it = 0; it < 8; ++it) {
        int idx = it * 256 + t;
        int nd = idx >> 5, g = idx & 31;
        uint4 v = make_uint4(0, 0, 0, 0);
        if (nd < nrem)
            v = (g < 16) ? h_g[(size_t)(node0 + nd) * 16 + g]
                         : comm[(size_t)(node0 + nd) * 16 + (g - 16)];
        LB[nd * 32 + g] = v;
        LW[idx] = WtA0[idx];
    }
    __syncthreads();

    const char* lb = (const char*)LB;
    const char* lw = (const char*)LW;

    // GEMM-A: combined^T = aggW^T [h|comm]^T  (K = 256, staged in halves)
    f32x16 c0 = {}, c1 = {};
    #pragma unroll
    for (int r = 0; r < 16; ++r) {
        int rr = (r & 3) + 8 * (r >> 2) + 4 * hh;
        c0[r] = agg_b[cp * 64 + rr];
        c1[r] = agg_b[cp * 64 + 32 + rr];
    }
    #pragma unroll
    for (int ks = 0; ks < 8; ++ks) {
        int so = ((ks * 2 + hh) ^ sw7) << 4;
        s16x8 bf = *(const s16x8*)(lb + nloc * 512 + so);
        s16x8 w0 = *(const s16x8*)(lw + (cp * 64 + l31) * 256 + so);
        s16x8 w1 = *(const s16x8*)(lw + (cp * 64 + 32 + l31) * 256 + so);
        c0 = __builtin_amdgcn_mfma_f32_32x32x16_bf16(w0, bf, c0, 0, 0, 0);
        c1 = __builtin_amdgcn_mfma_f32_32x32x16_bf16(w1, bf, c1, 0, 0, 0);
    }
    __syncthreads();
    #pragma unroll
    for (int it = 0; it < 8; ++it) LW[it * 256 + t] = WtA1[it * 256 + t];
    __syncthreads();
    #pragma unroll
    for (int ks = 8; ks < 16; ++ks) {
        int so = ((ks * 2 + hh) ^ sw7) << 4;            // bit4 kept: comm half
        int so2 = (((ks - 8) * 2 + hh) ^ sw7) << 4;
        s16x8 bf = *(const s16x8*)(lb + nloc * 512 + so);
        s16x8 w0 = *(const s16x8*)(lw + (cp * 64 + l31) * 256 + so2);
        s16x8 w1 = *(const s16x8*)(lw + (cp * 64 + 32 + l31) * 256 + so2);
        c0 = __builtin_amdgcn_mfma_f32_32x32x16_bf16(w0, bf, c0, 0, 0, 0);
        c1 = __builtin_amdgcn_mfma_f32_32x32x16_bf16(w1, bf, c1, 0, 0, 0);
    }
    __syncthreads();   // all Bcat / WtA1 reads done

    // relu + build combined fragments; exchange across waves via LB (Lcomb)
    {
        uint4 cf[4];
        BUILDR(cf[0], c0, 0, hh); BUILDR(cf[1], c0, 1, hh);
        BUILDR(cf[2], c1, 0, hh); BUILDR(cf[3], c1, 1, hh);
        #pragma unroll
        for (int f = 0; f < 4; ++f) {
            int g = (cp * 4 + f) * 2 + hh;
            LB[nloc * 16 + (g ^ sw7)] = cf[f];
        }
    }
    #pragma unroll
    for (int it = 0; it < 8; ++it) LW[it * 256 + t] = WtD[it * 256 + t];
    __syncthreads();

    // GEMM-B: out = combined @ dec_w  (A = in-LDS combined frags, lane = outcol)
    f32x16 o0 = {}, o1 = {};
    {
        float b0 = dec_b[cp * 64 + l31], b1 = dec_b[cp * 64 + 32 + l31];
        #pragma unroll
        for (int r = 0; r < 16; ++r) { o0[r] = b0; o1[r] = b1; }
    }
    #pragma unroll
    for (int ks = 0; ks < 8; ++ks) {
        int so = ((ks * 2 + hh) ^ sw7) << 4;
        s16x8 af = *(const s16x8*)(lb + nloc * 256 + so);
        s16x8 w0 = *(const s16x8*)(lw + (cp * 64 + l31) * 256 + so);
        s16x8 w1 = *(const s16x8*)(lw + (cp * 64 + 32 + l31) * 256 + so);
        o0 = __builtin_amdgcn_mfma_f32_32x32x16_bf16(af, w0, o0, 0, 0, 0);
        o1 = __builtin_amdgcn_mfma_f32_32x32x16_bf16(af, w1, o1, 0, 0, 0);
    }
    #pragma unroll
    for (int r = 0; r < 16; ++r) {
        int nd = ng * 32 + (r & 3) + 8 * (r >> 2) + 4 * hh;
        if (nd < nrem) {
            float* row = out + (size_t)(node0 + nd) * 128 + cp * 64;
            row[l31]      = o0[r];
            row[32 + l31] = o1[r];
        }
    }
}

// ---------------------------------------------------------------------------
// fused partB + aggr: one block per 64-node range. LDS ~17 KB.
//  phase 1: bin entries into LDS; den (f32) via LDS atomics
//  phase 2: PV — 2 nodes/wave (half-wave, lane = 4 dims), 4-way unrolled
//           batched independent gathers.
// ---------------------------------------------------------------------------
__global__ __launch_bounds__(256) void k_pb_aggr(
    const int* __restrict__ gcur, const u32* __restrict__ part,
    const u32* __restrict__ sig_bf,
    const char* __restrict__ msg_g, char* __restrict__ comm)
{
    __shared__ int   cnt[64];
    __shared__ float lden[64];
    __shared__ u32   lde[64 * CAP];   // 16 KB packed (d | fp16(e)<<16)

    const int t = threadIdx.x;
    const int r = blockIdx.x;
    const int node0 = r * 64;

    if (t < 64) { cnt[t] = 0; lden[t] = 0.f; }
    __syncthreads();

    const int total = gcur[r];
    for (int i = t; i < total; i += 256) {
        u32 en = part[(size_t)r * PCAP + i];
        int s = (int)(en >> 16), d = (int)(en & 0xFFFFu);
        const uint4* ps = (const uint4*)(sig_bf + (size_t)s * 8);
        const uint4* pd = (const uint4*)(sig_bf + (size_t)d * 8);
        uint4 sa = ps[0], sb = ps[1];
        uint4 da = pd[0], db = pd[1];
        float dot = dotpair(sa.x, da.x) + dotpair(sa.y, da.y)
                  + dotpair(sa.z, da.z) + dotpair(sa.w, da.w)
                  + dotpair(sb.x, db.x) + dotpair(sb.y, db.y)
                  + dotpair(sb.z, db.z) + dotpair(sb.w, db.w);
        float e = __expf(dot);   // |dot|<=1 (unit sigs): segment_max elision exact
        int sl = s & 63;
        int p = atomicAdd(&cnt[sl], 1);
        lde[sl * CAP + p] = (u32)d | ((u32)__half_as_ushort(__float2half(e)) << 16);
        atomicAdd(&lden[sl], e);
    }
    __syncthreads();

    // PV: wave wid covers nodes [wid*16, wid*16+16), 2 at a time (half-waves)
    const int lane = t & 63, wid = t >> 6;
    const int l31 = lane & 31, hh = lane >> 5;
    #pragma unroll
    for (int g = 0; g < 8; ++g) {
        const int nloc = wid * 16 + 2 * g + hh;
        const int node = node0 + nloc;
        const int cn = cnt[nloc];
        const u32* ld = &lde[nloc * CAP];
        float a0 = 0.f, a1 = 0.f, a2 = 0.f, a3 = 0.f;
        int k = 0;
        for (; k + 4 <= cn; k += 4) {
            u32 b0 = ld[k], b1 = ld[k + 1], b2 = ld[k + 2], b3 = ld[k + 3];
            uint2 m0 = *(const uint2*)(msg_g + (size_t)(b0 & 0xFFFFu) * 256 + 8 * l31);
            uint2 m1 = *(const uint2*)(msg_g + (size_t)(b1 & 0xFFFFu) * 256 + 8 * l31);
            uint2 m2 = *(const uint2*)(msg_g + (size_t)(b2 & 0xFFFFu) * 256 + 8 * l31);
            uint2 m3 = *(const uint2*)(msg_g + (size_t)(b3 & 0xFFFFu) * 256 + 8 * l31);
            float e0 = __half2float(__ushort_as_half((u16)(b0 >> 16)));
            float e1 = __half2float(__ushort_as_half((u16)(b1 >> 16)));
            float e2 = __half2float(__ushort_as_half((u16)(b2 >> 16)));
            float e3 = __half2float(__ushort_as_half((u16)(b3 >> 16)));
            a0 += e0 * bf2f(m0.x & 0xFFFFu); a1 += e0 * bf2f(m0.x >> 16);
            a2 += e0 * bf2f(m0.y & 0xFFFFu); a3 += e0 * bf2f(m0.y >> 16);
            a0 += e1 * bf2f(m1.x & 0xFFFFu); a1 += e1 * bf2f(m1.x >> 16);
            a2 += e1 * bf2f(m1.y & 0xFFFFu); a3 += e1 * bf2f(m1.y >> 16);
            a0 += e2 * bf2f(m2.x & 0xFFFFu); a1 += e2 * bf2f(m2.x >> 16);
            a2 += e2 * bf2f(m2.y & 0xFFFFu); a3 += e2 * bf2f(m2.y >> 16);
            a0 += e3 * bf2f(m3.x & 0xFFFFu); a1 += e3 * bf2f(m3.x >> 16);
            a2 += e3 * bf2f(m3.y & 0xFFFFu); a3 += e3 * bf2f(m3.y >> 16);
        }
        for (; k < cn; ++k) {
            u32 b = ld[k];
            float e = __half2float(__ushort_as_half((u16)(b >> 16)));
            uint2 m = *(const uint2*)(msg_g + (size_t)(b & 0xFFFFu) * 256 + 8 * l31);
            a0 += e * bf2f(m.x & 0xFFFFu);
            a1 += e * bf2f(m.x >> 16);
            a2 += e * bf2f(m.y & 0xFFFFu);
            a3 += e * bf2f(m.y >> 16);
        }
        float den = lden[nloc];
        float inv = (den > 0.f) ? (1.0f / den) : 0.f;
        if (node < N_NODES) {
            uint2 w;
            w.x = pkbf(a0 * inv, a1 * inv);
            w.y = pkbf(a2 * inv, a3 * inv);
            *(uint2*)(comm + (size_t)node * 256 + ((8 * l31) ^ ((node & 7) << 4))) = w;
        }
    }
}

// ---------------------------------------------------------------------------
extern "C" void kernel_launch(void* const* d_in, const int* in_sizes, int n_in,
                              void* d_out, int out_size, void* d_ws, size_t ws_size,
                              hipStream_t stream)
{
    const float* x     = (const float*)d_in[0];
    const int*   ei    = (const int*)  d_in[1];
    const float* enc_w = (const float*)d_in[2];
    const float* enc_b = (const float*)d_in[3];
    const float* sig_w = (const float*)d_in[4];
    const float* sig_b = (const float*)d_in[5];
    const float* msg_w = (const float*)d_in[6];
    const float* msg_b = (const float*)d_in[7];
    const float* agg_w = (const float*)d_in[8];
    const float* agg_b = (const float*)d_in[9];
    const float* dec_w = (const float*)d_in[10];
    const float* dec_b = (const float*)d_in[11];
    float* out = (float*)d_out;

    const int* src = ei;            // edge_index[0]
    const int* dst = ei + N_EDGES;  // edge_index[1]

    // workspace layout (bytes), ~45 MB
    char* p = (char*)d_ws;
    uint4* h_g   = (uint4*)p;  p += (size_t)N_NODES * 256;  // bf16 rows, swizzled
    uint4* msg_g = (uint4*)p;  p += (size_t)N_NODES * 256;  // bf16 rows, LINEAR
    uint4* comm  = (uint4*)p;  p += (size_t)N_NODES * 256;  // bf16 rows, swizzled
    u32*   sig_bf = (u32*)p;   p += (size_t)N_NODES * 32;   // bf16 sig rows
    u32*   part   = (u32*)p;   p += (size_t)NRANGE * PCAP * 4;
    int*   gcur   = (int*)p;   p += 4096;
    uint4* WtE  = (uint4*)p; p += 32768;
    uint4* WtM  = (uint4*)p; p += 32768;
    uint4* WtD  = (uint4*)p; p += 32768;
    uint4* WtA0 = (uint4*)p; p += 32768;
    uint4* WtA1 = (uint4*)p; p += 32768;
    uint4* WtS  = (uint4*)p; p += 8192;

    k_prep<<<42, 256, 0, stream>>>(enc_w, msg_w, sig_w, agg_w, dec_w,
                                   WtE, WtM, WtD, WtA0, WtA1, WtS, gcur);
    k_enc_part<<<NBA + NBE, 256, 0, stream>>>(
        x, WtE, WtM, WtS, enc_b, sig_b, msg_b, h_g, sig_bf, msg_g,
        src, dst, gcur, part);
    k_pb_aggr<<<NRANGE, 256, 0, stream>>>(
        gcur, part, sig_bf, (const char*)msg_g, (char*)comm);
    k_decode_m<<<(N_NODES + 63) / 64, 256, 0, stream>>>(
        h_g, comm, WtA0, WtA1, WtD, agg_b, dec_b, out);
}